// Round 3
// baseline (1480.211 us; speedup 1.0000x reference)
//
#include <hip/hip_runtime.h>
#include <math.h>

#define DD   128
#define NQQ  7
#define NB   1024
#define TRI  8256          // 128*129/2
#define LDA  132           // padded row stride for 128x128 f32 tiles
#define LDH  260           // padded row stride for rho staging (128 complex = 256 f32)
#define NSQ  3             // squarings  (scale = 1/8)
#define MTAY 11            // Taylor order; theta<=0.71 -> remainder ~3e-11

// acc += sgn * (A @ B) restricted to this thread's 4x8 output tile.
__device__ __forceinline__ void mm_acc(const float* A, const float* Bp,
                                       int r0, int c0, float acc[4][8], float sgn)
{
#pragma unroll 4
  for (int k = 0; k < DD; ++k) {
    float av[4];
#pragma unroll
    for (int a = 0; a < 4; ++a) av[a] = sgn * A[(r0 + a) * LDA + k];
    float4 b0 = *reinterpret_cast<const float4*>(&Bp[k * LDA + c0]);
    float4 b1 = *reinterpret_cast<const float4*>(&Bp[k * LDA + c0 + 4]);
    float bv[8] = {b0.x, b0.y, b0.z, b0.w, b1.x, b1.y, b1.z, b1.w};
#pragma unroll
    for (int a = 0; a < 4; ++a)
#pragma unroll
      for (int d = 0; d < 8; ++d)
        acc[a][d] = fmaf(av[a], bv[d], acc[a][d]);
  }
}

__global__ __launch_bounds__(512) void loss_k(
    const float* __restrict__ flat,   // B x TRI
    const float* __restrict__ timev,  // B
    const float* __restrict__ state,  // B x D x D x 2
    const int*   __restrict__ tgt,    // B
    const int*   __restrict__ basis,  // B x NQ
    float* __restrict__ ws)           // B per-block partial losses
{
  __shared__ float As[DD * LDA];     // 67584 B
  __shared__ float Bs[DD * LDA];     // 67584 B
  __shared__ float Hs[16 * LDH];     // 16640 B   (total 151808 B <= 160K)

  const int b   = blockIdx.x;
  const int tid = threadIdx.x;
  const int ty  = tid >> 4;          // 0..31 -> rows ty*4..+4
  const int tx  = tid & 15;          // 0..15 -> cols tx*8..+8
  const int r0  = ty * 4, c0 = tx * 8;

  const float t     = timev[b];
  const float alpha = 0.25f * t * 0.125f;   // DS * t / 2^NSQ

  // ---- Phase 0: build x = alpha*M into As, copy to Bs (T_1) ----
  const float* fb = flat + (size_t)b * TRI;
  for (int e = tid; e < DD * DD; e += 512) {
    int i = e >> 7, j = e & 127;
    int r = i >= j ? i : j;
    int c = i >= j ? j : i;
    float v = alpha * fb[(r * (r + 1)) / 2 + c];
    As[i * LDA + j] = v;
    Bs[i * LDA + j] = v;
  }
  __syncthreads();

  // ---- Phase 1: Taylor of exp(-i x) -> (ur, ui) in registers ----
  // exp(-i x) = sum_k (-i)^k x^k / k!;  As holds x, Bs holds T_{k-1}=x^{k-1}/(k-1)!
  float ur[4][8], ui[4][8];
#pragma unroll
  for (int a = 0; a < 4; ++a)
#pragma unroll
    for (int d = 0; d < 8; ++d) {
      ur[a][d] = ((r0 + a) == (c0 + d)) ? 1.0f : 0.0f;       // k=0 term
      ui[a][d] = -As[(r0 + a) * LDA + (c0 + d)];             // k=1 term: -i*x
    }

  for (int k = 2; k <= MTAY; ++k) {
    float r[4][8];
#pragma unroll
    for (int a = 0; a < 4; ++a)
#pragma unroll
      for (int d = 0; d < 8; ++d) r[a][d] = 0.0f;
    mm_acc(As, Bs, r0, c0, r, 1.0f);       // r = x @ T_{k-1}
    __syncthreads();
    const float ik = 1.0f / (float)k;
    const bool even = (k & 1) == 0;
    // (-i)^k: k%4==0:+re  1:-im  2:-re  3:+im
    const float sgn = (k & 2) ? ((k & 1) ? 1.0f : -1.0f)
                              : ((k & 1) ? -1.0f : 1.0f);
#pragma unroll
    for (int a = 0; a < 4; ++a)
#pragma unroll
      for (int d = 0; d < 8; ++d) {
        float v = r[a][d] * ik;            // T_k
        Bs[(r0 + a) * LDA + (c0 + d)] = v;
        if (even) ur[a][d] += sgn * v; else ui[a][d] += sgn * v;
      }
    __syncthreads();
  }

  // ---- Phase 2: write U0 into LDS (As=Re, Bs=Im), then NSQ squarings ----
#pragma unroll
  for (int a = 0; a < 4; ++a)
#pragma unroll
    for (int d = 0; d < 8; ++d) {
      As[(r0 + a) * LDA + (c0 + d)] = ur[a][d];
      Bs[(r0 + a) * LDA + (c0 + d)] = ui[a][d];
    }
  __syncthreads();

  // U^2 with Re,Im commuting (both polynomials in x):
  //   Re' = A@A - B@B ;  Im' = 2*(A@B)
  // Fused single k-pass: 96 FMA per k with 8 scalar + 4 b128 LDS reads.
  for (int sq = 0; sq < NSQ; ++sq) {
    float r1[4][8], r2[4][8];
#pragma unroll
    for (int a = 0; a < 4; ++a)
#pragma unroll
      for (int d = 0; d < 8; ++d) { r1[a][d] = 0.0f; r2[a][d] = 0.0f; }

#pragma unroll 2
    for (int k = 0; k < DD; ++k) {
      float ar[4], br[4];
#pragma unroll
      for (int a = 0; a < 4; ++a) {
        ar[a] = As[(r0 + a) * LDA + k];
        br[a] = Bs[(r0 + a) * LDA + k];
      }
      float4 ac0 = *reinterpret_cast<const float4*>(&As[k * LDA + c0]);
      float4 ac1 = *reinterpret_cast<const float4*>(&As[k * LDA + c0 + 4]);
      float4 bc0 = *reinterpret_cast<const float4*>(&Bs[k * LDA + c0]);
      float4 bc1 = *reinterpret_cast<const float4*>(&Bs[k * LDA + c0 + 4]);
      float acv[8] = {ac0.x, ac0.y, ac0.z, ac0.w, ac1.x, ac1.y, ac1.z, ac1.w};
      float bcv[8] = {bc0.x, bc0.y, bc0.z, bc0.w, bc1.x, bc1.y, bc1.z, bc1.w};
#pragma unroll
      for (int a = 0; a < 4; ++a)
#pragma unroll
        for (int d = 0; d < 8; ++d) {
          r1[a][d] = fmaf(ar[a], acv[d], r1[a][d]);
          r1[a][d] = fmaf(-br[a], bcv[d], r1[a][d]);
          r2[a][d] = fmaf(ar[a], bcv[d], r2[a][d]);
        }
    }
    __syncthreads();
#pragma unroll
    for (int a = 0; a < 4; ++a)
#pragma unroll
      for (int d = 0; d < 8; ++d) {
        As[(r0 + a) * LDA + (c0 + d)] = r1[a][d];
        Bs[(r0 + a) * LDA + (c0 + d)] = 2.0f * r2[a][d];
      }
    __syncthreads();
  }

  // ---- Phase 3: Kronecker butterfly G = F @ U, in place on rows ----
  const int* bq = basis + b * NQQ;
  const float sv = 0.70710678118654752f;
  for (int q = 0; q < NQQ; ++q) {
    int g = bq[q];
    if (g == 2) continue;                  // identity gate (uniform branch)
    const int bit = 6 - q;                 // qubit 0 = MSB
    float g00r, g00i, g01r, g01i, g10r, g10i, g11r, g11i;
    if (g == 0) {        // H
      g00r = sv; g00i = 0; g01r = sv;  g01i = 0;
      g10r = sv; g10i = 0; g11r = -sv; g11i = 0;
    } else {             // H @ S^dag = s*[[1,-i],[1,i]]
      g00r = sv; g00i = 0; g01r = 0; g01i = -sv;
      g10r = sv; g10i = 0; g11r = 0; g11i = sv;
    }
    for (int sidx = tid; sidx < 64 * DD; sidx += 512) {
      int c   = sidx & 127;
      int p   = sidx >> 7;                 // pair id 0..63
      int low = p & ((1 << bit) - 1);
      int i0  = ((p >> bit) << (bit + 1)) | low;
      int i1  = i0 | (1 << bit);
      float a0 = As[i0 * LDA + c], b0v = Bs[i0 * LDA + c];
      float a1 = As[i1 * LDA + c], b1v = Bs[i1 * LDA + c];
      float n0r = g00r * a0 - g00i * b0v + g01r * a1 - g01i * b1v;
      float n0i = g00r * b0v + g00i * a0 + g01r * b1v + g01i * a1;
      float n1r = g10r * a0 - g10i * b0v + g11r * a1 - g11i * b1v;
      float n1i = g10r * b0v + g10i * a0 + g11r * b1v + g11i * a1;
      As[i0 * LDA + c] = n0r; Bs[i0 * LDA + c] = n0i;
      As[i1 * LDA + c] = n1r; Bs[i1 * LDA + c] = n1i;
    }
    __syncthreads();
  }

  // ---- Phase 4: d_i = g_i @ rho @ g_i^H  (rho streamed in 16-row tiles) ----
  const float* st = state + (size_t)b * (DD * DD * 2);
  const int qi = tid >> 2;                 // row i = 0..127
  const int qh = tid & 3;                  // k-offset mod 4
  float dr = 0.0f, di = 0.0f;

  for (int tile = 0; tile < 8; ++tile) {
    {   // stage rho rows [16*tile, 16*tile+16) into Hs (re/im interleaved)
      int f  = tid * 8;
      int kk = f >> 8;                     // 0..15
      int x  = f & 255;
      const float* src = st + tile * 4096 + kk * 256 + x;
      float4 v0 = *reinterpret_cast<const float4*>(src);
      float4 v1 = *reinterpret_cast<const float4*>(src + 4);
      *reinterpret_cast<float4*>(&Hs[kk * LDH + x])     = v0;
      *reinterpret_cast<float4*>(&Hs[kk * LDH + x + 4]) = v1;
    }
    __syncthreads();

#pragma unroll
    for (int m = 0; m < 4; ++m) {
      int kk = qh + 4 * m;                 // k within tile
      float zr = 0.0f, zi = 0.0f;
      const float* hrow = &Hs[kk * LDH];
      const float* ar   = &As[qi * LDA];
      const float* br   = &Bs[qi * LDA];
#pragma unroll 2
      for (int l = 0; l < DD; l += 4) {
        float4 gr4 = *reinterpret_cast<const float4*>(ar + l);
        float4 gi4 = *reinterpret_cast<const float4*>(br + l);
        float4 h0  = *reinterpret_cast<const float4*>(hrow + 2 * l);
        float4 h1  = *reinterpret_cast<const float4*>(hrow + 2 * l + 4);
        // z_k += rho[k][l] * conj(g_i[l])
        zr = fmaf(h0.x, gr4.x, zr); zr = fmaf(h0.y, gi4.x, zr);
        zi = fmaf(h0.y, gr4.x, zi); zi = fmaf(-h0.x, gi4.x, zi);
        zr = fmaf(h0.z, gr4.y, zr); zr = fmaf(h0.w, gi4.y, zr);
        zi = fmaf(h0.w, gr4.y, zi); zi = fmaf(-h0.z, gi4.y, zi);
        zr = fmaf(h1.x, gr4.z, zr); zr = fmaf(h1.y, gi4.z, zr);
        zi = fmaf(h1.y, gr4.z, zi); zi = fmaf(-h1.x, gi4.z, zi);
        zr = fmaf(h1.z, gr4.w, zr); zr = fmaf(h1.w, gi4.w, zr);
        zi = fmaf(h1.w, gr4.w, zi); zi = fmaf(-h1.z, gi4.w, zi);
      }
      int k = tile * 16 + kk;
      float gr = As[qi * LDA + k], gi = Bs[qi * LDA + k];
      dr = fmaf(gr, zr, dr); dr = fmaf(-gi, zi, dr);
      di = fmaf(gr, zi, di); di = fmaf(gi, zr, di);
    }
    __syncthreads();
  }

  // reduce 4 k-partials per row (lanes 4i..4i+3 are in the same wave)
  dr += __shfl_xor(dr, 1); dr += __shfl_xor(dr, 2);
  di += __shfl_xor(di, 1); di += __shfl_xor(di, 2);
  __syncthreads();
  if ((tid & 3) == 0) Hs[qi] = dr * dr + di * di;   // |d_i|^2
  __syncthreads();

  if (tid < 64) {
    float ps = Hs[tid] + Hs[tid + 64];
#pragma unroll
    for (int o = 32; o >= 1; o >>= 1) ps += __shfl_xor(ps, o);
    if (tid == 0) {
      float pt = Hs[tgt[b]];
      float tp = pt / ps;
      tp = fmaxf(tp, 1e-12f);
      ws[b] = -logf(tp) * (1.0f / (float)NQQ);
    }
  }
}

// Deterministic 1024 -> 1 mean (no float atomics; stable vs rocprof replay).
__global__ __launch_bounds__(256) void reduce_k(const float* __restrict__ ws,
                                                float* __restrict__ out)
{
  __shared__ float s[256];
  const int tid = threadIdx.x;
  float v = ws[tid] + ws[tid + 256] + ws[tid + 512] + ws[tid + 768];
  s[tid] = v;
  __syncthreads();
  for (int o = 128; o > 0; o >>= 1) {
    if (tid < o) s[tid] += s[tid + o];
    __syncthreads();
  }
  if (tid == 0) out[0] = s[0] * (1.0f / (float)NB);
}

extern "C" void kernel_launch(void* const* d_in, const int* in_sizes, int n_in,
                              void* d_out, int out_size, void* d_ws, size_t ws_size,
                              hipStream_t stream) {
  const float* flat  = (const float*)d_in[0];
  const float* tv    = (const float*)d_in[1];
  const float* st    = (const float*)d_in[2];
  const int*   tgt   = (const int*)d_in[3];
  const int*   basis = (const int*)d_in[4];
  float* out = (float*)d_out;
  float* ws  = (float*)d_ws;

  hipLaunchKernelGGL(loss_k, dim3(NB), dim3(512), 0, stream,
                     flat, tv, st, tgt, basis, ws);
  hipLaunchKernelGGL(reduce_k, dim3(1), dim3(256), 0, stream, ws, out);
}

// Round 4
// 759.147 us; speedup vs baseline: 1.9498x; 1.9498x over previous
//
#include <hip/hip_runtime.h>
#include <math.h>

#define DD    128
#define NQQ   7
#define NB    1024
#define TRI   8256
#define NSQ   2          // squarings (scale 1/4)
#define MTAY  15         // Taylor order; theta<=1.45 -> remainder ~2e-11
#define CSTR  136        // bf16 elems per chunk row (272 B = 17 x 16B granules)
#define FSTR  132        // fp32 elems per row in fp32 overlay

typedef short  bf16x8 __attribute__((ext_vector_type(8)));
typedef short  s16x4  __attribute__((ext_vector_type(4)));
typedef float  f32x16 __attribute__((ext_vector_type(16)));

__device__ __forceinline__ unsigned short f2bf(float v) {
  unsigned u = __builtin_bit_cast(unsigned, v);
  u = (u + 0x7fffu + ((u >> 16) & 1u)) >> 16;   // RNE truncate to bf16
  return (unsigned short)u;
}
__device__ __forceinline__ float bf2f(unsigned short s) {
  unsigned u = ((unsigned)s) << 16;
  return __builtin_bit_cast(float, u);
}
__device__ __forceinline__ f32x16 MF(bf16x8 a, bf16x8 b, f32x16 c) {
  return __builtin_amdgcn_mfma_f32_32x32x16_bf16(a, b, c, 0, 0, 0);
}
__device__ __forceinline__ bf16x8 NEG(bf16x8 a) {
  int4 u = __builtin_bit_cast(int4, a);
  u.x ^= 0x80008000; u.y ^= 0x80008000; u.z ^= 0x80008000; u.w ^= 0x80008000;
  return __builtin_bit_cast(bf16x8, u);
}
__device__ __forceinline__ bf16x8 LDF(const unsigned short* C, int row, int s, int hb) {
  return *reinterpret_cast<const bf16x8*>(C + row * CSTR + s * 16 + hb * 8);
}

__global__ __launch_bounds__(512) void loss_k(
    const float* __restrict__ flat,
    const float* __restrict__ timev,
    const float* __restrict__ state,
    const int*   __restrict__ tgt,
    const int*   __restrict__ basis,
    float* __restrict__ ws)
{
  __shared__ __align__(16) char lds[4 * 128 * CSTR * 2 + 2048];
  unsigned short* C0 = (unsigned short*)lds;         // chunk bufs (bf16 hi/lo)
  unsigned short* C1 = C0 + 128 * CSTR;
  unsigned short* C2 = C1 + 128 * CSTR;
  unsigned short* C3 = C2 + 128 * CSTR;
  float* AUX = (float*)(lds + 4 * 128 * CSTR * 2);   // 512 floats
  float* Urf = (float*)lds;                          // fp32 overlay (aliases chunks)
  float* Uif = Urf + 128 * FSTR;

  const int b    = blockIdx.x;
  const int tid  = threadIdx.x;
  const int wid  = tid >> 6;
  const int lane = tid & 63;
  const int l31  = lane & 31;
  const int hb   = lane >> 5;

  const int tr    = wid >> 1;            // tile-row: rows 32*tr..+31
  const int tcb   = (wid & 1) * 2;       // tile-cols tcb, tcb+1
  const int arow  = 32 * tr + l31;       // A-frag row
  const int bcol0 = 32 * tcb + l31;      // B-frag col, tile 0
  const int bcol1 = 32 * (tcb + 1) + l31;

  // ---- Phase 0: x = alpha*M, split into bf16 hi/lo chunks (X and T1=X) ----
  const float tval  = timev[b];
  const float alpha = 0.25f * tval / (float)(1 << NSQ);
  const float* fb = flat + (size_t)b * TRI;
  for (int e = tid; e < DD * DD; e += 512) {
    int i = e >> 7, j = e & 127;
    int r = i >= j ? i : j, c = i >= j ? j : i;
    float v = alpha * fb[(r * (r + 1)) / 2 + c];
    unsigned short h = f2bf(v);
    unsigned short lo = f2bf(v - bf2f(h));
    C0[i * CSTR + j] = h;  C1[i * CSTR + j] = lo;
    C2[i * CSTR + j] = h;  C3[i * CSTR + j] = lo;
  }
  __syncthreads();

  // ---- U init: k=0 (I) and k=1 (-i x) terms, in C/D layout regs ----
  f32x16 ur0, ui0, ur1, ui1;
#pragma unroll
  for (int q = 0; q < 4; ++q) {
    int ro = 32 * tr + 8 * q + 4 * hb;
    s16x4 xh0 = *(const s16x4*)(C0 + bcol0 * CSTR + ro);
    s16x4 xl0 = *(const s16x4*)(C1 + bcol0 * CSTR + ro);
    s16x4 xh1 = *(const s16x4*)(C0 + bcol1 * CSTR + ro);
    s16x4 xl1 = *(const s16x4*)(C1 + bcol1 * CSTR + ro);
#pragma unroll
    for (int rr = 0; rr < 4; ++rr) {
      int e = 4 * q + rr;
      int rg = ro + rr;
      ur0[e] = (rg == bcol0) ? 1.0f : 0.0f;
      ur1[e] = (rg == bcol1) ? 1.0f : 0.0f;
      ui0[e] = -(bf2f((unsigned short)xh0[rr]) + bf2f((unsigned short)xl0[rr]));
      ui1[e] = -(bf2f((unsigned short)xh1[rr]) + bf2f((unsigned short)xl1[rr]));
    }
  }

  // ---- Taylor: T_k = (X @ T_{k-1})/k, U += (-i)^k T_k  (3-product bf16 split) ----
  for (int k = 2; k <= MTAY; ++k) {
    f32x16 p0, p1;
#pragma unroll
    for (int e = 0; e < 16; ++e) { p0[e] = 0.0f; p1[e] = 0.0f; }
#pragma unroll
    for (int s = 0; s < 8; ++s) {
      bf16x8 ah  = LDF(C0, arow, s, hb);
      bf16x8 al  = LDF(C1, arow, s, hb);
      bf16x8 b0h = LDF(C2, bcol0, s, hb);
      bf16x8 b0l = LDF(C3, bcol0, s, hb);
      bf16x8 b1h = LDF(C2, bcol1, s, hb);
      bf16x8 b1l = LDF(C3, bcol1, s, hb);
      p0 = MF(ah, b0h, p0); p0 = MF(ah, b0l, p0); p0 = MF(al, b0h, p0);
      p1 = MF(ah, b1h, p1); p1 = MF(ah, b1l, p1); p1 = MF(al, b1h, p1);
    }
    __syncthreads();
    const float ik = 1.0f / (float)k;
    const int m4 = k & 3;
#pragma unroll
    for (int e = 0; e < 16; ++e) {
      float v0 = p0[e] * ik, v1 = p1[e] * ik;
      if      (m4 == 0) { ur0[e] += v0; ur1[e] += v1; }
      else if (m4 == 1) { ui0[e] -= v0; ui1[e] -= v1; }
      else if (m4 == 2) { ur0[e] -= v0; ur1[e] -= v1; }
      else              { ui0[e] += v0; ui1[e] += v1; }
    }
    if (k < MTAY) {
#pragma unroll
      for (int q = 0; q < 4; ++q) {
        s16x4 h0, l0, h1, l1;
#pragma unroll
        for (int rr = 0; rr < 4; ++rr) {
          float v0 = p0[4 * q + rr] * ik;
          float v1 = p1[4 * q + rr] * ik;
          unsigned short hh0 = f2bf(v0); h0[rr] = (short)hh0; l0[rr] = (short)f2bf(v0 - bf2f(hh0));
          unsigned short hh1 = f2bf(v1); h1[rr] = (short)hh1; l1[rr] = (short)f2bf(v1 - bf2f(hh1));
        }
        int off0 = bcol0 * CSTR + 32 * tr + 8 * q + 4 * hb;
        int off1 = bcol1 * CSTR + 32 * tr + 8 * q + 4 * hb;
        *(s16x4*)(C2 + off0) = h0; *(s16x4*)(C3 + off0) = l0;
        *(s16x4*)(C2 + off1) = h1; *(s16x4*)(C3 + off1) = l1;
      }
    }
    __syncthreads();
  }

  // ---- Write U0 chunks: C0/C1=Re hi/lo, C2/C3=Im hi/lo ----
#pragma unroll
  for (int q = 0; q < 4; ++q) {
    s16x4 rh0, rl0, ih0, il0, rh1, rl1, ih1, il1;
#pragma unroll
    for (int rr = 0; rr < 4; ++rr) {
      int e = 4 * q + rr;
      unsigned short h;
      h = f2bf(ur0[e]); rh0[rr] = (short)h; rl0[rr] = (short)f2bf(ur0[e] - bf2f(h));
      h = f2bf(ur1[e]); rh1[rr] = (short)h; rl1[rr] = (short)f2bf(ur1[e] - bf2f(h));
      h = f2bf(ui0[e]); ih0[rr] = (short)h; il0[rr] = (short)f2bf(ui0[e] - bf2f(h));
      h = f2bf(ui1[e]); ih1[rr] = (short)h; il1[rr] = (short)f2bf(ui1[e] - bf2f(h));
    }
    int off0 = bcol0 * CSTR + 32 * tr + 8 * q + 4 * hb;
    int off1 = bcol1 * CSTR + 32 * tr + 8 * q + 4 * hb;
    *(s16x4*)(C0 + off0) = rh0; *(s16x4*)(C1 + off0) = rl0;
    *(s16x4*)(C2 + off0) = ih0; *(s16x4*)(C3 + off0) = il0;
    *(s16x4*)(C0 + off1) = rh1; *(s16x4*)(C1 + off1) = rl1;
    *(s16x4*)(C2 + off1) = ih1; *(s16x4*)(C3 + off1) = il1;
  }
  __syncthreads();

  // ---- Squarings: Re' = R@R - I@I ; Im' = 2*(R@I)  (commuting) ----
  for (int sq = 0; sq < NSQ; ++sq) {
    f32x16 cr0, ci0, cr1, ci1;
#pragma unroll
    for (int e = 0; e < 16; ++e) { cr0[e] = 0; ci0[e] = 0; cr1[e] = 0; ci1[e] = 0; }
#pragma unroll
    for (int s = 0; s < 8; ++s) {
      bf16x8 aRh = LDF(C0, arow, s, hb);
      bf16x8 aRl = LDF(C1, arow, s, hb);
      bf16x8 aIh = LDF(C2, arow, s, hb);
      bf16x8 aIl = LDF(C3, arow, s, hb);
      bf16x8 aIhN = NEG(aIh), aIlN = NEG(aIl);
      bf16x8 bRh0 = LDF(C0, bcol0, s, hb), bRl0 = LDF(C1, bcol0, s, hb);
      bf16x8 bIh0 = LDF(C2, bcol0, s, hb), bIl0 = LDF(C3, bcol0, s, hb);
      bf16x8 bRh1 = LDF(C0, bcol1, s, hb), bRl1 = LDF(C1, bcol1, s, hb);
      bf16x8 bIh1 = LDF(C2, bcol1, s, hb), bIl1 = LDF(C3, bcol1, s, hb);
      cr0 = MF(aRh, bRh0, cr0); cr0 = MF(aRh, bRl0, cr0); cr0 = MF(aRl, bRh0, cr0);
      cr0 = MF(aIhN, bIh0, cr0); cr0 = MF(aIhN, bIl0, cr0); cr0 = MF(aIlN, bIh0, cr0);
      ci0 = MF(aRh, bIh0, ci0); ci0 = MF(aRh, bIl0, ci0); ci0 = MF(aRl, bIh0, ci0);
      cr1 = MF(aRh, bRh1, cr1); cr1 = MF(aRh, bRl1, cr1); cr1 = MF(aRl, bRh1, cr1);
      cr1 = MF(aIhN, bIh1, cr1); cr1 = MF(aIhN, bIl1, cr1); cr1 = MF(aIlN, bIh1, cr1);
      ci1 = MF(aRh, bIh1, ci1); ci1 = MF(aRh, bIl1, ci1); ci1 = MF(aRl, bIh1, ci1);
    }
    __syncthreads();
    if (sq < NSQ - 1) {
#pragma unroll
      for (int q = 0; q < 4; ++q) {
        s16x4 rh0, rl0, ih0, il0, rh1, rl1, ih1, il1;
#pragma unroll
        for (int rr = 0; rr < 4; ++rr) {
          int e = 4 * q + rr;
          unsigned short h; float v;
          v = cr0[e];        h = f2bf(v); rh0[rr] = (short)h; rl0[rr] = (short)f2bf(v - bf2f(h));
          v = 2.0f * ci0[e]; h = f2bf(v); ih0[rr] = (short)h; il0[rr] = (short)f2bf(v - bf2f(h));
          v = cr1[e];        h = f2bf(v); rh1[rr] = (short)h; rl1[rr] = (short)f2bf(v - bf2f(h));
          v = 2.0f * ci1[e]; h = f2bf(v); ih1[rr] = (short)h; il1[rr] = (short)f2bf(v - bf2f(h));
        }
        int off0 = bcol0 * CSTR + 32 * tr + 8 * q + 4 * hb;
        int off1 = bcol1 * CSTR + 32 * tr + 8 * q + 4 * hb;
        *(s16x4*)(C0 + off0) = rh0; *(s16x4*)(C1 + off0) = rl0;
        *(s16x4*)(C2 + off0) = ih0; *(s16x4*)(C3 + off0) = il0;
        *(s16x4*)(C0 + off1) = rh1; *(s16x4*)(C1 + off1) = rl1;
        *(s16x4*)(C2 + off1) = ih1; *(s16x4*)(C3 + off1) = il1;
      }
    } else {
      // final squaring -> fp32 U into overlay (post-sync, overwrites chunks)
#pragma unroll
      for (int q = 0; q < 4; ++q) {
        int off0 = bcol0 * FSTR + 32 * tr + 8 * q + 4 * hb;
        int off1 = bcol1 * FSTR + 32 * tr + 8 * q + 4 * hb;
        *(float4*)(Urf + off0) = make_float4(cr0[4*q], cr0[4*q+1], cr0[4*q+2], cr0[4*q+3]);
        *(float4*)(Uif + off0) = make_float4(2.0f*ci0[4*q], 2.0f*ci0[4*q+1], 2.0f*ci0[4*q+2], 2.0f*ci0[4*q+3]);
        *(float4*)(Urf + off1) = make_float4(cr1[4*q], cr1[4*q+1], cr1[4*q+2], cr1[4*q+3]);
        *(float4*)(Uif + off1) = make_float4(2.0f*ci1[4*q], 2.0f*ci1[4*q+1], 2.0f*ci1[4*q+2], 2.0f*ci1[4*q+3]);
      }
    }
    __syncthreads();
  }

  // ---- Butterfly G = F @ U on fp32 overlay (rows mixed in place) ----
  const int* bq = basis + b * NQQ;
  const float sv = 0.70710678118654752f;
  for (int q = 0; q < NQQ; ++q) {
    int g = bq[q];
    if (g == 2) continue;            // uniform branch
    const int bit = 6 - q;
    float g00r, g01r, g01i, g10r, g11r, g11i;
    if (g == 0) { g00r = sv; g01r = sv; g01i = 0;   g10r = sv; g11r = -sv; g11i = 0;  }
    else        { g00r = sv; g01r = 0;  g01i = -sv; g10r = sv; g11r = 0;   g11i = sv; }
    for (int jj = tid; jj < 64 * 32; jj += 512) {
      int cg = jj & 31;
      int p  = jj >> 5;
      int low = p & ((1 << bit) - 1);
      int i0 = ((p >> bit) << (bit + 1)) | low;
      int i1 = i0 | (1 << bit);
      float4 a0 = *(float4*)(Urf + i0 * FSTR + 4 * cg);
      float4 b0 = *(float4*)(Uif + i0 * FSTR + 4 * cg);
      float4 a1 = *(float4*)(Urf + i1 * FSTR + 4 * cg);
      float4 b1 = *(float4*)(Uif + i1 * FSTR + 4 * cg);
      float4 n0r, n0i, n1r, n1i;
#define BFLY(cc) { \
      float A0 = a0.cc, B0 = b0.cc, A1 = a1.cc, B1 = b1.cc; \
      n0r.cc = g00r * A0 + g01r * A1 - g01i * B1; \
      n0i.cc = g00r * B0 + g01r * B1 + g01i * A1; \
      n1r.cc = g10r * A0 + g11r * A1 - g11i * B1; \
      n1i.cc = g10r * B0 + g11r * B1 + g11i * A1; }
      BFLY(x) BFLY(y) BFLY(z) BFLY(w)
#undef BFLY
      *(float4*)(Urf + i0 * FSTR + 4 * cg) = n0r;
      *(float4*)(Uif + i0 * FSTR + 4 * cg) = n0i;
      *(float4*)(Urf + i1 * FSTR + 4 * cg) = n1r;
      *(float4*)(Uif + i1 * FSTR + 4 * cg) = n1i;
    }
    __syncthreads();
  }

  // ---- Re-layout: fp32 G -> bf16 hi/lo chunks (in place, read-sync-write) ----
  {
    const int i  = tid >> 2;
    const int j0 = (tid & 3) * 32;
    float vr[32], vi[32];
#pragma unroll
    for (int c = 0; c < 8; ++c) {
      float4 x = *(float4*)(Urf + i * FSTR + j0 + 4 * c);
      vr[4*c+0] = x.x; vr[4*c+1] = x.y; vr[4*c+2] = x.z; vr[4*c+3] = x.w;
      float4 y = *(float4*)(Uif + i * FSTR + j0 + 4 * c);
      vi[4*c+0] = y.x; vi[4*c+1] = y.y; vi[4*c+2] = y.z; vi[4*c+3] = y.w;
    }
    __syncthreads();
#pragma unroll
    for (int blkc = 0; blkc < 4; ++blkc) {
      bf16x8 h, lo, h2, lo2;
#pragma unroll
      for (int e2 = 0; e2 < 8; ++e2) {
        float v = vr[blkc * 8 + e2];
        unsigned short hh = f2bf(v);
        h[e2] = (short)hh; lo[e2] = (short)f2bf(v - bf2f(hh));
        float w2 = vi[blkc * 8 + e2];
        unsigned short hh2 = f2bf(w2);
        h2[e2] = (short)hh2; lo2[e2] = (short)f2bf(w2 - bf2f(hh2));
      }
      int off = i * CSTR + j0 + blkc * 8;
      *(bf16x8*)(C0 + off) = h;  *(bf16x8*)(C1 + off) = lo;
      *(bf16x8*)(C2 + off) = h2; *(bf16x8*)(C3 + off) = lo2;
    }
    __syncthreads();
  }

  // ---- Phase 4: W = rho @ conj(G)^T (MFMA), d_i = sum_k G_ik W_ki ----
  const int n4   = wid & 3;      // W col-tile
  const int outk = wid >> 2;     // 0 -> Wr, 1 -> Wi
  const int gcol = 32 * n4 + l31;
  const float* st = state + (size_t)b * (DD * DD * 2);
  float acc1 = 0.0f, acc2 = 0.0f;
  for (int slab = 0; slab < 4; ++slab) {
    f32x16 w;
#pragma unroll
    for (int e = 0; e < 16; ++e) w[e] = 0.0f;
    const float* srow = st + (size_t)(32 * slab + l31) * 256;
#pragma unroll
    for (int s = 0; s < 8; ++s) {
      const float* pp = srow + (s * 16 + hb * 8) * 2;
      float4 q0 = *(const float4*)(pp);
      float4 q1 = *(const float4*)(pp + 4);
      float4 q2 = *(const float4*)(pp + 8);
      float4 q3 = *(const float4*)(pp + 12);
      float re[8] = {q0.x, q0.z, q1.x, q1.z, q2.x, q2.z, q3.x, q3.z};
      float im[8] = {q0.y, q0.w, q1.y, q1.w, q2.y, q2.w, q3.y, q3.w};
      bf16x8 rh, rl, ihh, ill;
#pragma unroll
      for (int e2 = 0; e2 < 8; ++e2) {
        unsigned short hh = f2bf(re[e2]); rh[e2] = (short)hh; rl[e2] = (short)f2bf(re[e2] - bf2f(hh));
        unsigned short h2 = f2bf(im[e2]); ihh[e2] = (short)h2; ill[e2] = (short)f2bf(im[e2] - bf2f(h2));
      }
      bf16x8 gRh = LDF(C0, gcol, s, hb), gRl = LDF(C1, gcol, s, hb);
      bf16x8 gIh = LDF(C2, gcol, s, hb), gIl = LDF(C3, gcol, s, hb);
      if (outk == 0) {     // Wr = rr@Gr + ri@Gi
        w = MF(rh, gRh, w); w = MF(rh, gRl, w); w = MF(rl, gRh, w);
        w = MF(ihh, gIh, w); w = MF(ihh, gIl, w); w = MF(ill, gIh, w);
      } else {             // Wi = ri@Gr - rr@Gi
        w = MF(ihh, gRh, w); w = MF(ihh, gRl, w); w = MF(ill, gRh, w);
        bf16x8 rhn = NEG(rh), rln = NEG(rl);
        w = MF(rhn, gIh, w); w = MF(rhn, gIl, w); w = MF(rln, gIh, w);
      }
    }
#pragma unroll
    for (int q = 0; q < 4; ++q) {
      int koff = 32 * slab + 8 * q + 4 * hb;
      s16x4 grh = *(const s16x4*)(C0 + gcol * CSTR + koff);
      s16x4 grl = *(const s16x4*)(C1 + gcol * CSTR + koff);
      s16x4 gih = *(const s16x4*)(C2 + gcol * CSTR + koff);
      s16x4 gil = *(const s16x4*)(C3 + gcol * CSTR + koff);
#pragma unroll
      for (int rr = 0; rr < 4; ++rr) {
        float wv = w[4 * q + rr];
        float gr = bf2f((unsigned short)grh[rr]) + bf2f((unsigned short)grl[rr]);
        float gi = bf2f((unsigned short)gih[rr]) + bf2f((unsigned short)gil[rr]);
        acc1 = fmaf(gr, wv, acc1);
        acc2 = fmaf(gi, wv, acc2);
      }
    }
  }
  acc1 += __shfl_xor(acc1, 32);
  acc2 += __shfl_xor(acc2, 32);
  if (lane < 32) {
    AUX[outk * 256 + gcol]       = acc1;   // outk0: GrWr / outk1: GrWi
    AUX[outk * 256 + 128 + gcol] = acc2;   // outk0: GiWr / outk1: GiWi
  }
  __syncthreads();

  if (tid < 128) {
    float dr = AUX[tid]       - AUX[384 + tid];
    float di = AUX[256 + tid] + AUX[128 + tid];
    AUX[tid] = dr * dr + di * di;
  }
  __syncthreads();
  if (tid < 64) {
    float ps = AUX[tid] + AUX[tid + 64];
#pragma unroll
    for (int o = 32; o >= 1; o >>= 1) ps += __shfl_xor(ps, o);
    if (tid == 0) {
      float pt = AUX[tgt[b]];
      float tp = fmaxf(pt / ps, 1e-12f);
      ws[b] = -logf(tp) * (1.0f / (float)NQQ);
    }
  }
}

// Deterministic 1024 -> 1 mean.
__global__ __launch_bounds__(256) void reduce_k(const float* __restrict__ ws,
                                                float* __restrict__ out)
{
  __shared__ float s[256];
  const int tid = threadIdx.x;
  float v = ws[tid] + ws[tid + 256] + ws[tid + 512] + ws[tid + 768];
  s[tid] = v;
  __syncthreads();
  for (int o = 128; o > 0; o >>= 1) {
    if (tid < o) s[tid] += s[tid + o];
    __syncthreads();
  }
  if (tid == 0) out[0] = s[0] * (1.0f / (float)NB);
}

extern "C" void kernel_launch(void* const* d_in, const int* in_sizes, int n_in,
                              void* d_out, int out_size, void* d_ws, size_t ws_size,
                              hipStream_t stream) {
  const float* flat  = (const float*)d_in[0];
  const float* tv    = (const float*)d_in[1];
  const float* st    = (const float*)d_in[2];
  const int*   tgt   = (const int*)d_in[3];
  const int*   basis = (const int*)d_in[4];
  float* out = (float*)d_out;
  float* ws  = (float*)d_ws;

  hipLaunchKernelGGL(loss_k, dim3(NB), dim3(512), 0, stream,
                     flat, tv, st, tgt, basis, ws);
  hipLaunchKernelGGL(reduce_k, dim3(1), dim3(256), 0, stream, ws, out);
}

// Round 5
// 521.853 us; speedup vs baseline: 2.8365x; 1.4547x over previous
//
#include <hip/hip_runtime.h>
#include <math.h>

#define DD    128
#define NQQ   7
#define NB    1024
#define TRI   8256
#define NSQ   2          // squarings (scale 1/4); theta<=1.45, Y-norm<=2.1
#define CSTR  136        // bf16 elems per chunk row (272 B = 17 x 16B granules)
#define FSTR  132        // fp32 elems per row in fp32 overlay

typedef short  bf16x8 __attribute__((ext_vector_type(8)));
typedef short  s16x4  __attribute__((ext_vector_type(4)));
typedef float  f32x16 __attribute__((ext_vector_type(16)));

// truncation hi/lo split: hi = top16(v), lo = top16(v - hi)  (~4 VALU ops)
__device__ __forceinline__ void split2(float v, unsigned short& h, unsigned short& l) {
  unsigned u = __builtin_bit_cast(unsigned, v);
  float hf = __builtin_bit_cast(float, u & 0xFFFF0000u);
  float lf = v - hf;
  h = (unsigned short)(u >> 16);
  l = (unsigned short)(__builtin_bit_cast(unsigned, lf) >> 16);
}
__device__ __forceinline__ float bf2f(unsigned short s) {
  return __builtin_bit_cast(float, ((unsigned)s) << 16);
}
__device__ __forceinline__ f32x16 MF(bf16x8 a, bf16x8 b, f32x16 c) {
  return __builtin_amdgcn_mfma_f32_32x32x16_bf16(a, b, c, 0, 0, 0);
}
__device__ __forceinline__ bf16x8 NEG(bf16x8 a) {
  int4 u = __builtin_bit_cast(int4, a);
  u.x ^= 0x80008000; u.y ^= 0x80008000; u.z ^= 0x80008000; u.w ^= 0x80008000;
  return __builtin_bit_cast(bf16x8, u);
}
__device__ __forceinline__ bf16x8 LDF(const unsigned short* C, int row, int s, int hb) {
  return *reinterpret_cast<const bf16x8*>(C + row * CSTR + s * 16 + hb * 8);
}

__global__ __launch_bounds__(512) void loss_k(
    const float* __restrict__ flat,
    const float* __restrict__ timev,
    const float* __restrict__ state,
    const int*   __restrict__ tgt,
    const int*   __restrict__ basis,
    float* __restrict__ ws)
{
  __shared__ __align__(16) char lds[4 * 128 * CSTR * 2 + 8192];
  unsigned short* C0 = (unsigned short*)lds;
  unsigned short* C1 = C0 + 128 * CSTR;
  unsigned short* C2 = C1 + 128 * CSTR;
  unsigned short* C3 = C2 + 128 * CSTR;
  float* AUX = (float*)(lds + 4 * 128 * CSTR * 2);   // 2048 floats
  float* Urf = (float*)lds;                          // fp32 overlay (aliases chunks)
  float* Uif = Urf + 128 * FSTR;

  const int b    = blockIdx.x;
  const int tid  = threadIdx.x;
  const int wid  = tid >> 6;
  const int lane = tid & 63;
  const int l31  = lane & 31;
  const int hb   = lane >> 5;

  const int tr    = wid >> 1;
  const int tcb   = (wid & 1) * 2;
  const int arow  = 32 * tr + l31;
  const int bcol0 = 32 * tcb + l31;
  const int bcol1 = 32 * (tcb + 1) + l31;

  const float tval  = timev[b];
  const float alpha = 0.25f * tval * 0.25f;     // DS * t / 2^NSQ
  const float* fb = flat + (size_t)b * TRI;

  // store a product-register tile (scaled) as hi/lo chunks at column BCOL
#define STORE_TILE(PREG, SCALE, BCOL, DH, DL) do {                         \
    _Pragma("unroll")                                                      \
    for (int q_ = 0; q_ < 4; ++q_) {                                       \
      s16x4 hh_, ll_;                                                      \
      _Pragma("unroll")                                                    \
      for (int rr_ = 0; rr_ < 4; ++rr_) {                                  \
        unsigned short h_, l_;                                             \
        split2((SCALE) * (PREG)[4 * q_ + rr_], h_, l_);                    \
        hh_[rr_] = (short)h_; ll_[rr_] = (short)l_;                        \
      }                                                                    \
      int off_ = (BCOL) * CSTR + 32 * tr + 8 * q_ + 4 * hb;                \
      *(s16x4*)((DH) + off_) = hh_; *(s16x4*)((DL) + off_) = ll_;          \
    }                                                                      \
  } while (0)

  // ---- Phase 0: stage X = alpha*M into C0/C1 (hi/lo) ----
  for (int e = tid; e < DD * DD; e += 512) {
    int i = e >> 7, j = e & 127;
    int r = i >= j ? i : j, c = i >= j ? j : i;
    float v = alpha * fb[(r * (r + 1)) / 2 + c];
    unsigned short h, l; split2(v, h, l);
    C0[i * CSTR + j] = h;  C1[i * CSTR + j] = l;
  }
  __syncthreads();

  f32x16 p0, p1, Cc0, Cc1, Qc0, Qc1;

  // ---- Y = X @ X ----
#pragma unroll
  for (int e = 0; e < 16; ++e) { p0[e] = 0.0f; p1[e] = 0.0f; }
#pragma unroll
  for (int s = 0; s < 8; ++s) {
    bf16x8 ah = LDF(C0, arow, s, hb),  al = LDF(C1, arow, s, hb);
    bf16x8 b0h = LDF(C0, bcol0, s, hb), b0l = LDF(C1, bcol0, s, hb);
    bf16x8 b1h = LDF(C0, bcol1, s, hb), b1l = LDF(C1, bcol1, s, hb);
    p0 = MF(ah, b0h, p0); p0 = MF(ah, b0l, p0); p0 = MF(al, b0h, p0);
    p1 = MF(ah, b1h, p1); p1 = MF(ah, b1l, p1); p1 = MF(al, b1h, p1);
  }
  __syncthreads();
  // init C = I - Y/2 + ..., Q = I - Y/6 + ...
#pragma unroll
  for (int q = 0; q < 4; ++q) {
#pragma unroll
    for (int rr = 0; rr < 4; ++rr) {
      int e = 4 * q + rr;
      int rg = 32 * tr + 8 * q + 4 * hb + rr;
      float i0 = (rg == bcol0) ? 1.0f : 0.0f;
      float i1 = (rg == bcol1) ? 1.0f : 0.0f;
      Cc0[e] = i0 - 0.5f * p0[e];            Cc1[e] = i1 - 0.5f * p1[e];
      Qc0[e] = i0 - 0.16666667f * p0[e];     Qc1[e] = i1 - 0.16666667f * p1[e];
    }
  }
  STORE_TILE(p0, 1.0f, bcol0, C2, C3);       // Y -> C2/C3
  STORE_TILE(p1, 1.0f, bcol1, C2, C3);
  __syncthreads();

  // ---- j=2: Z2 = Y @ Y -> C0/C1 (X dead, rebuilt later) ----
#pragma unroll
  for (int e = 0; e < 16; ++e) { p0[e] = 0.0f; p1[e] = 0.0f; }
#pragma unroll
  for (int s = 0; s < 8; ++s) {
    bf16x8 ah = LDF(C2, arow, s, hb),  al = LDF(C3, arow, s, hb);
    bf16x8 b0h = LDF(C2, bcol0, s, hb), b0l = LDF(C3, bcol0, s, hb);
    bf16x8 b1h = LDF(C2, bcol1, s, hb), b1l = LDF(C3, bcol1, s, hb);
    p0 = MF(ah, b0h, p0); p0 = MF(ah, b0l, p0); p0 = MF(al, b0h, p0);
    p1 = MF(ah, b1h, p1); p1 = MF(ah, b1l, p1); p1 = MF(al, b1h, p1);
  }
  __syncthreads();
#pragma unroll
  for (int e = 0; e < 16; ++e) {
    Cc0[e] += 4.1666668e-2f * p0[e];  Cc1[e] += 4.1666668e-2f * p1[e];
    Qc0[e] += 8.3333333e-3f * p0[e];  Qc1[e] += 8.3333333e-3f * p1[e];
  }
  STORE_TILE(p0, 1.0f, bcol0, C0, C1);
  STORE_TILE(p1, 1.0f, bcol1, C0, C1);
  __syncthreads();

  // ---- j=3..8: Z_j = Y @ Z_{j-1}; C += c_j Z_j; Q += q_j Z_j (j<8) ----
  const float CJ[9] = {0.f, 0.f, 0.f, -1.3888889e-3f, 2.4801587e-5f,
                       -2.7557319e-7f, 2.0876757e-9f, -1.1470746e-11f, 4.7794773e-14f};
  const float QJ[8] = {0.f, 0.f, 0.f, -1.9841270e-4f, 2.7557319e-6f,
                       -2.5052108e-8f, 1.6059044e-10f, -7.6471637e-13f};
#pragma unroll
  for (int j = 3; j <= 8; ++j) {
#pragma unroll
    for (int e = 0; e < 16; ++e) { p0[e] = 0.0f; p1[e] = 0.0f; }
#pragma unroll
    for (int s = 0; s < 8; ++s) {
      bf16x8 ah = LDF(C2, arow, s, hb),  al = LDF(C3, arow, s, hb);
      bf16x8 b0h = LDF(C0, bcol0, s, hb), b0l = LDF(C1, bcol0, s, hb);
      bf16x8 b1h = LDF(C0, bcol1, s, hb), b1l = LDF(C1, bcol1, s, hb);
      p0 = MF(ah, b0h, p0); p0 = MF(ah, b0l, p0); p0 = MF(al, b0h, p0);
      p1 = MF(ah, b1h, p1); p1 = MF(ah, b1l, p1); p1 = MF(al, b1h, p1);
    }
    __syncthreads();
#pragma unroll
    for (int e = 0; e < 16; ++e) { Cc0[e] += CJ[j] * p0[e]; Cc1[e] += CJ[j] * p1[e]; }
    if (j < 8) {
#pragma unroll
      for (int e = 0; e < 16; ++e) { Qc0[e] += QJ[j] * p0[e]; Qc1[e] += QJ[j] * p1[e]; }
      STORE_TILE(p0, 1.0f, bcol0, C0, C1);
      STORE_TILE(p1, 1.0f, bcol1, C0, C1);
    }
    __syncthreads();
  }

  // ---- Write Q -> C2/C3 (over Y); rebuild X -> C0/C1 (over Z7) ----
  STORE_TILE(Qc0, 1.0f, bcol0, C2, C3);
  STORE_TILE(Qc1, 1.0f, bcol1, C2, C3);
  for (int e = tid; e < DD * DD; e += 512) {
    int i = e >> 7, j = e & 127;
    int r = i >= j ? i : j, c = i >= j ? j : i;
    float v = alpha * fb[(r * (r + 1)) / 2 + c];
    unsigned short h, l; split2(v, h, l);
    C0[i * CSTR + j] = h;  C1[i * CSTR + j] = l;
  }
  __syncthreads();

  // ---- S = X @ Q  (sin) ----
#pragma unroll
  for (int e = 0; e < 16; ++e) { p0[e] = 0.0f; p1[e] = 0.0f; }
#pragma unroll
  for (int s = 0; s < 8; ++s) {
    bf16x8 ah = LDF(C0, arow, s, hb),  al = LDF(C1, arow, s, hb);
    bf16x8 b0h = LDF(C2, bcol0, s, hb), b0l = LDF(C3, bcol0, s, hb);
    bf16x8 b1h = LDF(C2, bcol1, s, hb), b1l = LDF(C3, bcol1, s, hb);
    p0 = MF(ah, b0h, p0); p0 = MF(ah, b0l, p0); p0 = MF(al, b0h, p0);
    p1 = MF(ah, b1h, p1); p1 = MF(ah, b1l, p1); p1 = MF(al, b1h, p1);
  }
  __syncthreads();

  // ---- U0 = cos - i sin: C0/C1 = Re hi/lo, C2/C3 = Im hi/lo ----
  STORE_TILE(Cc0, 1.0f, bcol0, C0, C1);
  STORE_TILE(Cc1, 1.0f, bcol1, C0, C1);
  STORE_TILE(p0, -1.0f, bcol0, C2, C3);
  STORE_TILE(p1, -1.0f, bcol1, C2, C3);
  __syncthreads();

  // ---- Squarings: Re' = R@R - I@I ; Im' = 2*(R@I) ----
  for (int sq = 0; sq < NSQ; ++sq) {
    f32x16 cr0, ci0, cr1, ci1;
#pragma unroll
    for (int e = 0; e < 16; ++e) { cr0[e] = 0; ci0[e] = 0; cr1[e] = 0; ci1[e] = 0; }
#pragma unroll
    for (int s = 0; s < 8; ++s) {
      bf16x8 aRh = LDF(C0, arow, s, hb), aRl = LDF(C1, arow, s, hb);
      bf16x8 aIh = LDF(C2, arow, s, hb), aIl = LDF(C3, arow, s, hb);
      bf16x8 aIhN = NEG(aIh), aIlN = NEG(aIl);
      bf16x8 bRh0 = LDF(C0, bcol0, s, hb), bRl0 = LDF(C1, bcol0, s, hb);
      bf16x8 bIh0 = LDF(C2, bcol0, s, hb), bIl0 = LDF(C3, bcol0, s, hb);
      bf16x8 bRh1 = LDF(C0, bcol1, s, hb), bRl1 = LDF(C1, bcol1, s, hb);
      bf16x8 bIh1 = LDF(C2, bcol1, s, hb), bIl1 = LDF(C3, bcol1, s, hb);
      cr0 = MF(aRh, bRh0, cr0); cr0 = MF(aRh, bRl0, cr0); cr0 = MF(aRl, bRh0, cr0);
      cr0 = MF(aIhN, bIh0, cr0); cr0 = MF(aIhN, bIl0, cr0); cr0 = MF(aIlN, bIh0, cr0);
      ci0 = MF(aRh, bIh0, ci0); ci0 = MF(aRh, bIl0, ci0); ci0 = MF(aRl, bIh0, ci0);
      cr1 = MF(aRh, bRh1, cr1); cr1 = MF(aRh, bRl1, cr1); cr1 = MF(aRl, bRh1, cr1);
      cr1 = MF(aIhN, bIh1, cr1); cr1 = MF(aIhN, bIl1, cr1); cr1 = MF(aIlN, bIh1, cr1);
      ci1 = MF(aRh, bIh1, ci1); ci1 = MF(aRh, bIl1, ci1); ci1 = MF(aRl, bIh1, ci1);
    }
    __syncthreads();
    if (sq < NSQ - 1) {
      STORE_TILE(cr0, 1.0f, bcol0, C0, C1);
      STORE_TILE(ci0, 2.0f, bcol0, C2, C3);
      STORE_TILE(cr1, 1.0f, bcol1, C0, C1);
      STORE_TILE(ci1, 2.0f, bcol1, C2, C3);
    } else {
#pragma unroll
      for (int q = 0; q < 4; ++q) {
        int off0 = bcol0 * FSTR + 32 * tr + 8 * q + 4 * hb;
        int off1 = bcol1 * FSTR + 32 * tr + 8 * q + 4 * hb;
        *(float4*)(Urf + off0) = make_float4(cr0[4*q], cr0[4*q+1], cr0[4*q+2], cr0[4*q+3]);
        *(float4*)(Uif + off0) = make_float4(2.0f*ci0[4*q], 2.0f*ci0[4*q+1], 2.0f*ci0[4*q+2], 2.0f*ci0[4*q+3]);
        *(float4*)(Urf + off1) = make_float4(cr1[4*q], cr1[4*q+1], cr1[4*q+2], cr1[4*q+3]);
        *(float4*)(Uif + off1) = make_float4(2.0f*ci1[4*q], 2.0f*ci1[4*q+1], 2.0f*ci1[4*q+2], 2.0f*ci1[4*q+3]);
      }
    }
    __syncthreads();
  }

  // ---- Butterfly G = F @ U on fp32 overlay ----
  const int* bq = basis + b * NQQ;
  const float sv = 0.70710678118654752f;
  for (int q = 0; q < NQQ; ++q) {
    int g = bq[q];
    if (g == 2) continue;
    const int bit = 6 - q;
    float g00r, g01r, g01i, g10r, g11r, g11i;
    if (g == 0) { g00r = sv; g01r = sv; g01i = 0;   g10r = sv; g11r = -sv; g11i = 0;  }
    else        { g00r = sv; g01r = 0;  g01i = -sv; g10r = sv; g11r = 0;   g11i = sv; }
    for (int jj = tid; jj < 64 * 32; jj += 512) {
      int cg = jj & 31;
      int p  = jj >> 5;
      int low = p & ((1 << bit) - 1);
      int i0 = ((p >> bit) << (bit + 1)) | low;
      int i1 = i0 | (1 << bit);
      float4 a0 = *(float4*)(Urf + i0 * FSTR + 4 * cg);
      float4 b0 = *(float4*)(Uif + i0 * FSTR + 4 * cg);
      float4 a1 = *(float4*)(Urf + i1 * FSTR + 4 * cg);
      float4 b1 = *(float4*)(Uif + i1 * FSTR + 4 * cg);
      float4 n0r, n0i, n1r, n1i;
#define BFLY(cc) { \
      float A0 = a0.cc, B0 = b0.cc, A1 = a1.cc, B1 = b1.cc; \
      n0r.cc = g00r * A0 + g01r * A1 - g01i * B1; \
      n0i.cc = g00r * B0 + g01r * B1 + g01i * A1; \
      n1r.cc = g10r * A0 + g11r * A1 - g11i * B1; \
      n1i.cc = g10r * B0 + g11r * B1 + g11i * A1; }
      BFLY(x) BFLY(y) BFLY(z) BFLY(w)
#undef BFLY
      *(float4*)(Urf + i0 * FSTR + 4 * cg) = n0r;
      *(float4*)(Uif + i0 * FSTR + 4 * cg) = n0i;
      *(float4*)(Urf + i1 * FSTR + 4 * cg) = n1r;
      *(float4*)(Uif + i1 * FSTR + 4 * cg) = n1i;
    }
    __syncthreads();
  }

  // ---- Re-layout fp32 G -> bf16 chunks ----
  {
    const int i  = tid >> 2;
    const int j0 = (tid & 3) * 32;
    float vr[32], vi[32];
#pragma unroll
    for (int c = 0; c < 8; ++c) {
      float4 x = *(float4*)(Urf + i * FSTR + j0 + 4 * c);
      vr[4*c+0] = x.x; vr[4*c+1] = x.y; vr[4*c+2] = x.z; vr[4*c+3] = x.w;
      float4 y = *(float4*)(Uif + i * FSTR + j0 + 4 * c);
      vi[4*c+0] = y.x; vi[4*c+1] = y.y; vi[4*c+2] = y.z; vi[4*c+3] = y.w;
    }
    __syncthreads();
#pragma unroll
    for (int blkc = 0; blkc < 4; ++blkc) {
      bf16x8 h, lo, h2, lo2;
#pragma unroll
      for (int e2 = 0; e2 < 8; ++e2) {
        unsigned short hh, ll;
        split2(vr[blkc * 8 + e2], hh, ll);  h[e2] = (short)hh;  lo[e2] = (short)ll;
        split2(vi[blkc * 8 + e2], hh, ll);  h2[e2] = (short)hh; lo2[e2] = (short)ll;
      }
      int off = i * CSTR + j0 + blkc * 8;
      *(bf16x8*)(C0 + off) = h;  *(bf16x8*)(C1 + off) = lo;
      *(bf16x8*)(C2 + off) = h2; *(bf16x8*)(C3 + off) = lo2;
    }
    __syncthreads();
  }

  // ---- Phase 4: W = rho @ conj(G)^T; d_i = sum_k G_ik W_ki ----
  // wave -> (slab = M block of W, part = Re/Im of W); rho converted once per s.
  const int slab = wid >> 1;
  const int part = wid & 1;
  const float* srow = state + (size_t)b * (DD * DD * 2) + (size_t)(32 * slab + l31) * 256;
  f32x16 w0, w1, w2, w3;
#pragma unroll
  for (int e = 0; e < 16; ++e) { w0[e] = 0; w1[e] = 0; w2[e] = 0; w3[e] = 0; }

  for (int s = 0; s < 8; ++s) {
    const float* pp = srow + (s * 16 + hb * 8) * 2;
    float4 q0 = *(const float4*)(pp);
    float4 q1 = *(const float4*)(pp + 4);
    float4 q2 = *(const float4*)(pp + 8);
    float4 q3 = *(const float4*)(pp + 12);
    float re[8] = {q0.x, q0.z, q1.x, q1.z, q2.x, q2.z, q3.x, q3.z};
    float im[8] = {q0.y, q0.w, q1.y, q1.w, q2.y, q2.w, q3.y, q3.w};
    bf16x8 rh, rl, ihh, ill;
#pragma unroll
    for (int e2 = 0; e2 < 8; ++e2) {
      unsigned short hh, ll;
      split2(re[e2], hh, ll); rh[e2] = (short)hh;  rl[e2] = (short)ll;
      split2(im[e2], hh, ll); ihh[e2] = (short)hh; ill[e2] = (short)ll;
    }
    bf16x8 rhn = NEG(rh), rln = NEG(rl);
#define P4N4(WREG, N4) do {                                                \
    int gcol_ = 32 * (N4) + l31;                                           \
    bf16x8 gRh = LDF(C0, gcol_, s, hb), gRl = LDF(C1, gcol_, s, hb);       \
    bf16x8 gIh = LDF(C2, gcol_, s, hb), gIl = LDF(C3, gcol_, s, hb);       \
    if (part == 0) {                                                       \
      WREG = MF(rh, gRh, WREG);  WREG = MF(rh, gRl, WREG);  WREG = MF(rl, gRh, WREG); \
      WREG = MF(ihh, gIh, WREG); WREG = MF(ihh, gIl, WREG); WREG = MF(ill, gIh, WREG); \
    } else {                                                               \
      WREG = MF(ihh, gRh, WREG); WREG = MF(ihh, gRl, WREG); WREG = MF(ill, gRh, WREG); \
      WREG = MF(rhn, gIh, WREG); WREG = MF(rhn, gIl, WREG); WREG = MF(rln, gIh, WREG); \
    }                                                                      \
  } while (0)
    P4N4(w0, 0); P4N4(w1, 1); P4N4(w2, 2); P4N4(w3, 3);
#undef P4N4
  }

  // dot: partial_{which}[i] over this slab's k-range
#define P4DOT(WREG, N4) do {                                               \
    int gcol_ = 32 * (N4) + l31;                                           \
    float a1 = 0.0f, a2 = 0.0f;                                            \
    _Pragma("unroll")                                                      \
    for (int q_ = 0; q_ < 4; ++q_) {                                       \
      int koff = 32 * slab + 8 * q_ + 4 * hb;                              \
      s16x4 grh = *(const s16x4*)(C0 + gcol_ * CSTR + koff);               \
      s16x4 grl = *(const s16x4*)(C1 + gcol_ * CSTR + koff);               \
      s16x4 gih = *(const s16x4*)(C2 + gcol_ * CSTR + koff);               \
      s16x4 gil = *(const s16x4*)(C3 + gcol_ * CSTR + koff);               \
      _Pragma("unroll")                                                    \
      for (int rr_ = 0; rr_ < 4; ++rr_) {                                  \
        float wv = WREG[4 * q_ + rr_];                                     \
        float gr = bf2f((unsigned short)grh[rr_]) + bf2f((unsigned short)grl[rr_]); \
        float gi = bf2f((unsigned short)gih[rr_]) + bf2f((unsigned short)gil[rr_]); \
        a1 = fmaf(gr, wv, a1); a2 = fmaf(gi, wv, a2);                      \
      }                                                                    \
    }                                                                      \
    a1 += __shfl_xor(a1, 32); a2 += __shfl_xor(a2, 32);                    \
    if (lane < 32) {                                                       \
      AUX[((part * 2 + 0) * 4 + slab) * 128 + 32 * (N4) + l31] = a1;       \
      AUX[((part * 2 + 1) * 4 + slab) * 128 + 32 * (N4) + l31] = a2;       \
    }                                                                      \
  } while (0)
  P4DOT(w0, 0); P4DOT(w1, 1); P4DOT(w2, 2); P4DOT(w3, 3);
#undef P4DOT
  __syncthreads();

  if (tid < 128) {
    float s0 = 0, s1 = 0, s2 = 0, s3 = 0;
#pragma unroll
    for (int sl = 0; sl < 4; ++sl) {
      s0 += AUX[(0 * 4 + sl) * 128 + tid];   // Gr.Wr
      s1 += AUX[(1 * 4 + sl) * 128 + tid];   // Gi.Wr
      s2 += AUX[(2 * 4 + sl) * 128 + tid];   // Gr.Wi
      s3 += AUX[(3 * 4 + sl) * 128 + tid];   // Gi.Wi
    }
    float dr = s0 - s3, di = s2 + s1;
    AUX[tid] = dr * dr + di * di;
  }
  __syncthreads();
  if (tid < 64) {
    float ps = AUX[tid] + AUX[tid + 64];
#pragma unroll
    for (int o = 32; o >= 1; o >>= 1) ps += __shfl_xor(ps, o);
    if (tid == 0) {
      float pt = AUX[tgt[b]];
      float tp = fmaxf(pt / ps, 1e-12f);
      ws[b] = -logf(tp) * (1.0f / (float)NQQ);
    }
  }
#undef STORE_TILE
}

// Deterministic 1024 -> 1 mean.
__global__ __launch_bounds__(256) void reduce_k(const float* __restrict__ ws,
                                                float* __restrict__ out)
{
  __shared__ float s[256];
  const int tid = threadIdx.x;
  float v = ws[tid] + ws[tid + 256] + ws[tid + 512] + ws[tid + 768];
  s[tid] = v;
  __syncthreads();
  for (int o = 128; o > 0; o >>= 1) {
    if (tid < o) s[tid] += s[tid + o];
    __syncthreads();
  }
  if (tid == 0) out[0] = s[0] * (1.0f / (float)NB);
}

extern "C" void kernel_launch(void* const* d_in, const int* in_sizes, int n_in,
                              void* d_out, int out_size, void* d_ws, size_t ws_size,
                              hipStream_t stream) {
  const float* flat  = (const float*)d_in[0];
  const float* tv    = (const float*)d_in[1];
  const float* st    = (const float*)d_in[2];
  const int*   tgt   = (const int*)d_in[3];
  const int*   basis = (const int*)d_in[4];
  float* out = (float*)d_out;
  float* ws  = (float*)d_ws;

  hipLaunchKernelGGL(loss_k, dim3(NB), dim3(512), 0, stream,
                     flat, tv, st, tgt, basis, ws);
  hipLaunchKernelGGL(reduce_k, dim3(1), dim3(256), 0, stream, ws, out);
}

// Round 6
// 516.309 us; speedup vs baseline: 2.8669x; 1.0107x over previous
//
#include <hip/hip_runtime.h>
#include <math.h>

#define DD    128
#define NQQ   7
#define NB    1024
#define TRI   8256
#define NSQ   2          // squarings (scale 1/4); theta<=1.45, Y-norm<=2.1
#define CSTR  136        // bf16 elems per chunk row (272 B = 17 x 16B granules)
#define FSTR  132        // fp32 elems per row in fp32 overlay

typedef short  bf16x8 __attribute__((ext_vector_type(8)));
typedef short  s16x4  __attribute__((ext_vector_type(4)));
typedef float  f32x16 __attribute__((ext_vector_type(16)));

// truncation hi/lo split: hi = top16(v), lo = top16(v - hi)  (~4 VALU ops)
__device__ __forceinline__ void split2(float v, unsigned short& h, unsigned short& l) {
  unsigned u = __builtin_bit_cast(unsigned, v);
  float hf = __builtin_bit_cast(float, u & 0xFFFF0000u);
  float lf = v - hf;
  h = (unsigned short)(u >> 16);
  l = (unsigned short)(__builtin_bit_cast(unsigned, lf) >> 16);
}
__device__ __forceinline__ float bf2f(unsigned short s) {
  return __builtin_bit_cast(float, ((unsigned)s) << 16);
}
__device__ __forceinline__ f32x16 MF(bf16x8 a, bf16x8 b, f32x16 c) {
  return __builtin_amdgcn_mfma_f32_32x32x16_bf16(a, b, c, 0, 0, 0);
}
__device__ __forceinline__ bf16x8 NEG(bf16x8 a) {
  int4 u = __builtin_bit_cast(int4, a);
  u.x ^= 0x80008000; u.y ^= 0x80008000; u.z ^= 0x80008000; u.w ^= 0x80008000;
  return __builtin_bit_cast(bf16x8, u);
}
__device__ __forceinline__ bf16x8 LDF(const unsigned short* C, int row, int s, int hb) {
  return *reinterpret_cast<const bf16x8*>(C + row * CSTR + s * 16 + hb * 8);
}

// __launch_bounds__(512, 2): block is 8 waves = 2 waves/EU (LDS already caps
// us at 1 block/CU), so cap VGPRs at 256/wave. The bare (512) form let the
// compiler target 128 VGPRs -> ~550MB/dispatch scratch spill (R5 counters).
__global__ __launch_bounds__(512, 2) void loss_k(
    const float* __restrict__ flat,
    const float* __restrict__ timev,
    const float* __restrict__ state,
    const int*   __restrict__ tgt,
    const int*   __restrict__ basis,
    float* __restrict__ ws)
{
  __shared__ __align__(16) char lds[4 * 128 * CSTR * 2 + 8192];
  unsigned short* C0 = (unsigned short*)lds;
  unsigned short* C1 = C0 + 128 * CSTR;
  unsigned short* C2 = C1 + 128 * CSTR;
  unsigned short* C3 = C2 + 128 * CSTR;
  float* AUX = (float*)(lds + 4 * 128 * CSTR * 2);   // 2048 floats
  float* Urf = (float*)lds;                          // fp32 overlay (aliases chunks)
  float* Uif = Urf + 128 * FSTR;

  const int b    = blockIdx.x;
  const int tid  = threadIdx.x;
  const int wid  = tid >> 6;
  const int lane = tid & 63;
  const int l31  = lane & 31;
  const int hb   = lane >> 5;

  const int tr    = wid >> 1;
  const int tcb   = (wid & 1) * 2;
  const int arow  = 32 * tr + l31;
  const int bcol0 = 32 * tcb + l31;
  const int bcol1 = 32 * (tcb + 1) + l31;

  const float tval  = timev[b];
  const float alpha = 0.25f * tval * 0.25f;     // DS * t / 2^NSQ
  const float* fb = flat + (size_t)b * TRI;

  // store a product-register tile (scaled) as hi/lo chunks at column BCOL
#define STORE_TILE(PREG, SCALE, BCOL, DH, DL) do {                         \
    _Pragma("unroll")                                                      \
    for (int q_ = 0; q_ < 4; ++q_) {                                       \
      s16x4 hh_, ll_;                                                      \
      _Pragma("unroll")                                                    \
      for (int rr_ = 0; rr_ < 4; ++rr_) {                                  \
        unsigned short h_, l_;                                             \
        split2((SCALE) * (PREG)[4 * q_ + rr_], h_, l_);                    \
        hh_[rr_] = (short)h_; ll_[rr_] = (short)l_;                        \
      }                                                                    \
      int off_ = (BCOL) * CSTR + 32 * tr + 8 * q_ + 4 * hb;                \
      *(s16x4*)((DH) + off_) = hh_; *(s16x4*)((DL) + off_) = ll_;          \
    }                                                                      \
  } while (0)

  // ---- Phase 0: stage X = alpha*M into C0/C1 (hi/lo) ----
  for (int e = tid; e < DD * DD; e += 512) {
    int i = e >> 7, j = e & 127;
    int r = i >= j ? i : j, c = i >= j ? j : i;
    float v = alpha * fb[(r * (r + 1)) / 2 + c];
    unsigned short h, l; split2(v, h, l);
    C0[i * CSTR + j] = h;  C1[i * CSTR + j] = l;
  }
  __syncthreads();

  f32x16 p0, p1, Cc0, Cc1, Qc0, Qc1;

  // ---- Y = X @ X ----
#pragma unroll
  for (int e = 0; e < 16; ++e) { p0[e] = 0.0f; p1[e] = 0.0f; }
#pragma unroll
  for (int s = 0; s < 8; ++s) {
    bf16x8 ah = LDF(C0, arow, s, hb),  al = LDF(C1, arow, s, hb);
    bf16x8 b0h = LDF(C0, bcol0, s, hb), b0l = LDF(C1, bcol0, s, hb);
    bf16x8 b1h = LDF(C0, bcol1, s, hb), b1l = LDF(C1, bcol1, s, hb);
    p0 = MF(ah, b0h, p0); p0 = MF(ah, b0l, p0); p0 = MF(al, b0h, p0);
    p1 = MF(ah, b1h, p1); p1 = MF(ah, b1l, p1); p1 = MF(al, b1h, p1);
  }
  __syncthreads();
  // init C = I - Y/2 + ..., Q = I - Y/6 + ...
#pragma unroll
  for (int q = 0; q < 4; ++q) {
#pragma unroll
    for (int rr = 0; rr < 4; ++rr) {
      int e = 4 * q + rr;
      int rg = 32 * tr + 8 * q + 4 * hb + rr;
      float i0 = (rg == bcol0) ? 1.0f : 0.0f;
      float i1 = (rg == bcol1) ? 1.0f : 0.0f;
      Cc0[e] = i0 - 0.5f * p0[e];            Cc1[e] = i1 - 0.5f * p1[e];
      Qc0[e] = i0 - 0.16666667f * p0[e];     Qc1[e] = i1 - 0.16666667f * p1[e];
    }
  }
  STORE_TILE(p0, 1.0f, bcol0, C2, C3);       // Y -> C2/C3
  STORE_TILE(p1, 1.0f, bcol1, C2, C3);
  __syncthreads();

  // ---- j=2: Z2 = Y @ Y -> C0/C1 (X dead, rebuilt later) ----
#pragma unroll
  for (int e = 0; e < 16; ++e) { p0[e] = 0.0f; p1[e] = 0.0f; }
#pragma unroll
  for (int s = 0; s < 8; ++s) {
    bf16x8 ah = LDF(C2, arow, s, hb),  al = LDF(C3, arow, s, hb);
    bf16x8 b0h = LDF(C2, bcol0, s, hb), b0l = LDF(C3, bcol0, s, hb);
    bf16x8 b1h = LDF(C2, bcol1, s, hb), b1l = LDF(C3, bcol1, s, hb);
    p0 = MF(ah, b0h, p0); p0 = MF(ah, b0l, p0); p0 = MF(al, b0h, p0);
    p1 = MF(ah, b1h, p1); p1 = MF(ah, b1l, p1); p1 = MF(al, b1h, p1);
  }
  __syncthreads();
#pragma unroll
  for (int e = 0; e < 16; ++e) {
    Cc0[e] += 4.1666668e-2f * p0[e];  Cc1[e] += 4.1666668e-2f * p1[e];
    Qc0[e] += 8.3333333e-3f * p0[e];  Qc1[e] += 8.3333333e-3f * p1[e];
  }
  STORE_TILE(p0, 1.0f, bcol0, C0, C1);
  STORE_TILE(p1, 1.0f, bcol1, C0, C1);
  __syncthreads();

  // ---- j=3..8: Z_j = Y @ Z_{j-1}; C += c_j Z_j; Q += q_j Z_j (j<8) ----
  const float CJ[9] = {0.f, 0.f, 0.f, -1.3888889e-3f, 2.4801587e-5f,
                       -2.7557319e-7f, 2.0876757e-9f, -1.1470746e-11f, 4.7794773e-14f};
  const float QJ[8] = {0.f, 0.f, 0.f, -1.9841270e-4f, 2.7557319e-6f,
                       -2.5052108e-8f, 1.6059044e-10f, -7.6471637e-13f};
#pragma unroll
  for (int j = 3; j <= 8; ++j) {
#pragma unroll
    for (int e = 0; e < 16; ++e) { p0[e] = 0.0f; p1[e] = 0.0f; }
#pragma unroll
    for (int s = 0; s < 8; ++s) {
      bf16x8 ah = LDF(C2, arow, s, hb),  al = LDF(C3, arow, s, hb);
      bf16x8 b0h = LDF(C0, bcol0, s, hb), b0l = LDF(C1, bcol0, s, hb);
      bf16x8 b1h = LDF(C0, bcol1, s, hb), b1l = LDF(C1, bcol1, s, hb);
      p0 = MF(ah, b0h, p0); p0 = MF(ah, b0l, p0); p0 = MF(al, b0h, p0);
      p1 = MF(ah, b1h, p1); p1 = MF(ah, b1l, p1); p1 = MF(al, b1h, p1);
    }
    __syncthreads();
#pragma unroll
    for (int e = 0; e < 16; ++e) { Cc0[e] += CJ[j] * p0[e]; Cc1[e] += CJ[j] * p1[e]; }
    if (j < 8) {
#pragma unroll
      for (int e = 0; e < 16; ++e) { Qc0[e] += QJ[j] * p0[e]; Qc1[e] += QJ[j] * p1[e]; }
      STORE_TILE(p0, 1.0f, bcol0, C0, C1);
      STORE_TILE(p1, 1.0f, bcol1, C0, C1);
    }
    __syncthreads();
  }

  // ---- Write Q -> C2/C3 (over Y); rebuild X -> C0/C1 (over Z7) ----
  STORE_TILE(Qc0, 1.0f, bcol0, C2, C3);
  STORE_TILE(Qc1, 1.0f, bcol1, C2, C3);
  for (int e = tid; e < DD * DD; e += 512) {
    int i = e >> 7, j = e & 127;
    int r = i >= j ? i : j, c = i >= j ? j : i;
    float v = alpha * fb[(r * (r + 1)) / 2 + c];
    unsigned short h, l; split2(v, h, l);
    C0[i * CSTR + j] = h;  C1[i * CSTR + j] = l;
  }
  __syncthreads();

  // ---- S = X @ Q  (sin) ----
#pragma unroll
  for (int e = 0; e < 16; ++e) { p0[e] = 0.0f; p1[e] = 0.0f; }
#pragma unroll
  for (int s = 0; s < 8; ++s) {
    bf16x8 ah = LDF(C0, arow, s, hb),  al = LDF(C1, arow, s, hb);
    bf16x8 b0h = LDF(C2, bcol0, s, hb), b0l = LDF(C3, bcol0, s, hb);
    bf16x8 b1h = LDF(C2, bcol1, s, hb), b1l = LDF(C3, bcol1, s, hb);
    p0 = MF(ah, b0h, p0); p0 = MF(ah, b0l, p0); p0 = MF(al, b0h, p0);
    p1 = MF(ah, b1h, p1); p1 = MF(ah, b1l, p1); p1 = MF(al, b1h, p1);
  }
  __syncthreads();

  // ---- U0 = cos - i sin: C0/C1 = Re hi/lo, C2/C3 = Im hi/lo ----
  STORE_TILE(Cc0, 1.0f, bcol0, C0, C1);
  STORE_TILE(Cc1, 1.0f, bcol1, C0, C1);
  STORE_TILE(p0, -1.0f, bcol0, C2, C3);
  STORE_TILE(p1, -1.0f, bcol1, C2, C3);
  __syncthreads();

  // ---- Squarings: Re' = R@R - I@I ; Im' = 2*(R@I) ----
  for (int sq = 0; sq < NSQ; ++sq) {
    f32x16 cr0, ci0, cr1, ci1;
#pragma unroll
    for (int e = 0; e < 16; ++e) { cr0[e] = 0; ci0[e] = 0; cr1[e] = 0; ci1[e] = 0; }
#pragma unroll
    for (int s = 0; s < 8; ++s) {
      bf16x8 aRh = LDF(C0, arow, s, hb), aRl = LDF(C1, arow, s, hb);
      bf16x8 aIh = LDF(C2, arow, s, hb), aIl = LDF(C3, arow, s, hb);
      bf16x8 aIhN = NEG(aIh), aIlN = NEG(aIl);
      bf16x8 bRh0 = LDF(C0, bcol0, s, hb), bRl0 = LDF(C1, bcol0, s, hb);
      bf16x8 bIh0 = LDF(C2, bcol0, s, hb), bIl0 = LDF(C3, bcol0, s, hb);
      bf16x8 bRh1 = LDF(C0, bcol1, s, hb), bRl1 = LDF(C1, bcol1, s, hb);
      bf16x8 bIh1 = LDF(C2, bcol1, s, hb), bIl1 = LDF(C3, bcol1, s, hb);
      cr0 = MF(aRh, bRh0, cr0); cr0 = MF(aRh, bRl0, cr0); cr0 = MF(aRl, bRh0, cr0);
      cr0 = MF(aIhN, bIh0, cr0); cr0 = MF(aIhN, bIl0, cr0); cr0 = MF(aIlN, bIh0, cr0);
      ci0 = MF(aRh, bIh0, ci0); ci0 = MF(aRh, bIl0, ci0); ci0 = MF(aRl, bIh0, ci0);
      cr1 = MF(aRh, bRh1, cr1); cr1 = MF(aRh, bRl1, cr1); cr1 = MF(aRl, bRh1, cr1);
      cr1 = MF(aIhN, bIh1, cr1); cr1 = MF(aIhN, bIl1, cr1); cr1 = MF(aIlN, bIh1, cr1);
      ci1 = MF(aRh, bIh1, ci1); ci1 = MF(aRh, bIl1, ci1); ci1 = MF(aRl, bIh1, ci1);
    }
    __syncthreads();
    if (sq < NSQ - 1) {
      STORE_TILE(cr0, 1.0f, bcol0, C0, C1);
      STORE_TILE(ci0, 2.0f, bcol0, C2, C3);
      STORE_TILE(cr1, 1.0f, bcol1, C0, C1);
      STORE_TILE(ci1, 2.0f, bcol1, C2, C3);
    } else {
#pragma unroll
      for (int q = 0; q < 4; ++q) {
        int off0 = bcol0 * FSTR + 32 * tr + 8 * q + 4 * hb;
        int off1 = bcol1 * FSTR + 32 * tr + 8 * q + 4 * hb;
        *(float4*)(Urf + off0) = make_float4(cr0[4*q], cr0[4*q+1], cr0[4*q+2], cr0[4*q+3]);
        *(float4*)(Uif + off0) = make_float4(2.0f*ci0[4*q], 2.0f*ci0[4*q+1], 2.0f*ci0[4*q+2], 2.0f*ci0[4*q+3]);
        *(float4*)(Urf + off1) = make_float4(cr1[4*q], cr1[4*q+1], cr1[4*q+2], cr1[4*q+3]);
        *(float4*)(Uif + off1) = make_float4(2.0f*ci1[4*q], 2.0f*ci1[4*q+1], 2.0f*ci1[4*q+2], 2.0f*ci1[4*q+3]);
      }
    }
    __syncthreads();
  }

  // ---- Butterfly G = F @ U on fp32 overlay ----
  const int* bq = basis + b * NQQ;
  const float sv = 0.70710678118654752f;
  for (int q = 0; q < NQQ; ++q) {
    int g = bq[q];
    if (g == 2) continue;
    const int bit = 6 - q;
    float g00r, g01r, g01i, g10r, g11r, g11i;
    if (g == 0) { g00r = sv; g01r = sv; g01i = 0;   g10r = sv; g11r = -sv; g11i = 0;  }
    else        { g00r = sv; g01r = 0;  g01i = -sv; g10r = sv; g11r = 0;   g11i = sv; }
    for (int jj = tid; jj < 64 * 32; jj += 512) {
      int cg = jj & 31;
      int p  = jj >> 5;
      int low = p & ((1 << bit) - 1);
      int i0 = ((p >> bit) << (bit + 1)) | low;
      int i1 = i0 | (1 << bit);
      float4 a0 = *(float4*)(Urf + i0 * FSTR + 4 * cg);
      float4 b0 = *(float4*)(Uif + i0 * FSTR + 4 * cg);
      float4 a1 = *(float4*)(Urf + i1 * FSTR + 4 * cg);
      float4 b1 = *(float4*)(Uif + i1 * FSTR + 4 * cg);
      float4 n0r, n0i, n1r, n1i;
#define BFLY(cc) { \
      float A0 = a0.cc, B0 = b0.cc, A1 = a1.cc, B1 = b1.cc; \
      n0r.cc = g00r * A0 + g01r * A1 - g01i * B1; \
      n0i.cc = g00r * B0 + g01r * B1 + g01i * A1; \
      n1r.cc = g10r * A0 + g11r * A1 - g11i * B1; \
      n1i.cc = g10r * B0 + g11r * B1 + g11i * A1; }
      BFLY(x) BFLY(y) BFLY(z) BFLY(w)
#undef BFLY
      *(float4*)(Urf + i0 * FSTR + 4 * cg) = n0r;
      *(float4*)(Uif + i0 * FSTR + 4 * cg) = n0i;
      *(float4*)(Urf + i1 * FSTR + 4 * cg) = n1r;
      *(float4*)(Uif + i1 * FSTR + 4 * cg) = n1i;
    }
    __syncthreads();
  }

  // ---- Re-layout fp32 G -> bf16 chunks ----
  {
    const int i  = tid >> 2;
    const int j0 = (tid & 3) * 32;
    float vr[32], vi[32];
#pragma unroll
    for (int c = 0; c < 8; ++c) {
      float4 x = *(float4*)(Urf + i * FSTR + j0 + 4 * c);
      vr[4*c+0] = x.x; vr[4*c+1] = x.y; vr[4*c+2] = x.z; vr[4*c+3] = x.w;
      float4 y = *(float4*)(Uif + i * FSTR + j0 + 4 * c);
      vi[4*c+0] = y.x; vi[4*c+1] = y.y; vi[4*c+2] = y.z; vi[4*c+3] = y.w;
    }
    __syncthreads();
#pragma unroll
    for (int blkc = 0; blkc < 4; ++blkc) {
      bf16x8 h, lo, h2, lo2;
#pragma unroll
      for (int e2 = 0; e2 < 8; ++e2) {
        unsigned short hh, ll;
        split2(vr[blkc * 8 + e2], hh, ll);  h[e2] = (short)hh;  lo[e2] = (short)ll;
        split2(vi[blkc * 8 + e2], hh, ll);  h2[e2] = (short)hh; lo2[e2] = (short)ll;
      }
      int off = i * CSTR + j0 + blkc * 8;
      *(bf16x8*)(C0 + off) = h;  *(bf16x8*)(C1 + off) = lo;
      *(bf16x8*)(C2 + off) = h2; *(bf16x8*)(C3 + off) = lo2;
    }
    __syncthreads();
  }

  // ---- Phase 4: W = rho @ conj(G)^T; d_i = sum_k G_ik W_ki ----
  // wave -> (slab = M block of W, part = Re/Im of W); rho converted once per s.
  const int slab = wid >> 1;
  const int part = wid & 1;
  const float* srow = state + (size_t)b * (DD * DD * 2) + (size_t)(32 * slab + l31) * 256;
  f32x16 w0, w1, w2, w3;
#pragma unroll
  for (int e = 0; e < 16; ++e) { w0[e] = 0; w1[e] = 0; w2[e] = 0; w3[e] = 0; }

  for (int s = 0; s < 8; ++s) {
    const float* pp = srow + (s * 16 + hb * 8) * 2;
    float4 q0 = *(const float4*)(pp);
    float4 q1 = *(const float4*)(pp + 4);
    float4 q2 = *(const float4*)(pp + 8);
    float4 q3 = *(const float4*)(pp + 12);
    float re[8] = {q0.x, q0.z, q1.x, q1.z, q2.x, q2.z, q3.x, q3.z};
    float im[8] = {q0.y, q0.w, q1.y, q1.w, q2.y, q2.w, q3.y, q3.w};
    bf16x8 rh, rl, ihh, ill;
#pragma unroll
    for (int e2 = 0; e2 < 8; ++e2) {
      unsigned short hh, ll;
      split2(re[e2], hh, ll); rh[e2] = (short)hh;  rl[e2] = (short)ll;
      split2(im[e2], hh, ll); ihh[e2] = (short)hh; ill[e2] = (short)ll;
    }
    bf16x8 rhn = NEG(rh), rln = NEG(rl);
#define P4N4(WREG, N4) do {                                                \
    int gcol_ = 32 * (N4) + l31;                                           \
    bf16x8 gRh = LDF(C0, gcol_, s, hb), gRl = LDF(C1, gcol_, s, hb);       \
    bf16x8 gIh = LDF(C2, gcol_, s, hb), gIl = LDF(C3, gcol_, s, hb);       \
    if (part == 0) {                                                       \
      WREG = MF(rh, gRh, WREG);  WREG = MF(rh, gRl, WREG);  WREG = MF(rl, gRh, WREG); \
      WREG = MF(ihh, gIh, WREG); WREG = MF(ihh, gIl, WREG); WREG = MF(ill, gIh, WREG); \
    } else {                                                               \
      WREG = MF(ihh, gRh, WREG); WREG = MF(ihh, gRl, WREG); WREG = MF(ill, gRh, WREG); \
      WREG = MF(rhn, gIh, WREG); WREG = MF(rhn, gIl, WREG); WREG = MF(rln, gIh, WREG); \
    }                                                                      \
  } while (0)
    P4N4(w0, 0); P4N4(w1, 1); P4N4(w2, 2); P4N4(w3, 3);
#undef P4N4
  }

  // dot: partial_{which}[i] over this slab's k-range
#define P4DOT(WREG, N4) do {                                               \
    int gcol_ = 32 * (N4) + l31;                                           \
    float a1 = 0.0f, a2 = 0.0f;                                            \
    _Pragma("unroll")                                                      \
    for (int q_ = 0; q_ < 4; ++q_) {                                       \
      int koff = 32 * slab + 8 * q_ + 4 * hb;                              \
      s16x4 grh = *(const s16x4*)(C0 + gcol_ * CSTR + koff);               \
      s16x4 grl = *(const s16x4*)(C1 + gcol_ * CSTR + koff);               \
      s16x4 gih = *(const s16x4*)(C2 + gcol_ * CSTR + koff);               \
      s16x4 gil = *(const s16x4*)(C3 + gcol_ * CSTR + koff);               \
      _Pragma("unroll")                                                    \
      for (int rr_ = 0; rr_ < 4; ++rr_) {                                  \
        float wv = WREG[4 * q_ + rr_];                                     \
        float gr = bf2f((unsigned short)grh[rr_]) + bf2f((unsigned short)grl[rr_]); \
        float gi = bf2f((unsigned short)gih[rr_]) + bf2f((unsigned short)gil[rr_]); \
        a1 = fmaf(gr, wv, a1); a2 = fmaf(gi, wv, a2);                      \
      }                                                                    \
    }                                                                      \
    a1 += __shfl_xor(a1, 32); a2 += __shfl_xor(a2, 32);                    \
    if (lane < 32) {                                                       \
      AUX[((part * 2 + 0) * 4 + slab) * 128 + 32 * (N4) + l31] = a1;       \
      AUX[((part * 2 + 1) * 4 + slab) * 128 + 32 * (N4) + l31] = a2;       \
    }                                                                      \
  } while (0)
  P4DOT(w0, 0); P4DOT(w1, 1); P4DOT(w2, 2); P4DOT(w3, 3);
#undef P4DOT
  __syncthreads();

  if (tid < 128) {
    float s0 = 0, s1 = 0, s2 = 0, s3 = 0;
#pragma unroll
    for (int sl = 0; sl < 4; ++sl) {
      s0 += AUX[(0 * 4 + sl) * 128 + tid];   // Gr.Wr
      s1 += AUX[(1 * 4 + sl) * 128 + tid];   // Gi.Wr
      s2 += AUX[(2 * 4 + sl) * 128 + tid];   // Gr.Wi
      s3 += AUX[(3 * 4 + sl) * 128 + tid];   // Gi.Wi
    }
    float dr = s0 - s3, di = s2 + s1;
    AUX[tid] = dr * dr + di * di;
  }
  __syncthreads();
  if (tid < 64) {
    float ps = AUX[tid] + AUX[tid + 64];
#pragma unroll
    for (int o = 32; o >= 1; o >>= 1) ps += __shfl_xor(ps, o);
    if (tid == 0) {
      float pt = AUX[tgt[b]];
      float tp = fmaxf(pt / ps, 1e-12f);
      ws[b] = -logf(tp) * (1.0f / (float)NQQ);
    }
  }
#undef STORE_TILE
}

// Deterministic 1024 -> 1 mean.
__global__ __launch_bounds__(256) void reduce_k(const float* __restrict__ ws,
                                                float* __restrict__ out)
{
  __shared__ float s[256];
  const int tid = threadIdx.x;
  float v = ws[tid] + ws[tid + 256] + ws[tid + 512] + ws[tid + 768];
  s[tid] = v;
  __syncthreads();
  for (int o = 128; o > 0; o >>= 1) {
    if (tid < o) s[tid] += s[tid + o];
    __syncthreads();
  }
  if (tid == 0) out[0] = s[0] * (1.0f / (float)NB);
}

extern "C" void kernel_launch(void* const* d_in, const int* in_sizes, int n_in,
                              void* d_out, int out_size, void* d_ws, size_t ws_size,
                              hipStream_t stream) {
  const float* flat  = (const float*)d_in[0];
  const float* tv    = (const float*)d_in[1];
  const float* st    = (const float*)d_in[2];
  const int*   tgt   = (const int*)d_in[3];
  const int*   basis = (const int*)d_in[4];
  float* out = (float*)d_out;
  float* ws  = (float*)d_ws;

  hipLaunchKernelGGL(loss_k, dim3(NB), dim3(512), 0, stream,
                     flat, tv, st, tgt, basis, ws);
  hipLaunchKernelGGL(reduce_k, dim3(1), dim3(256), 0, stream, ws, out);
}